// Round 8
// baseline (608.223 us; speedup 1.0000x reference)
//
#include <hip/hip_runtime.h>
#include <math.h>

#define DI __device__ __forceinline__

constexpr int B_ = 8, C_ = 64, H_ = 62, T_ = 400, S_ = 32;
constexpr int HT   = H_ * T_;      // 24800
constexpr int CHT  = C_ * HT;      // 1587200
constexpr int NPOS = B_ * HT;      // 198400
constexpr int NTOT = B_ * CHT;     // 12697600

DI float sigmoidf_(float x) { return 1.f / (1.f + expf(-x)); }
DI float gelu_(float x) { return 0.5f * x * (1.f + erff(x * 0.70710678118654752f)); }

template<int ACT> DI float act_(float v) {
  if (ACT == 1) return fmaxf(v, 0.f);
  if (ACT == 2) return sigmoidf_(v);
  return v;
}

// ---------- prep: transpose pointwise weights to [c][o], fold bn gain ----------
__global__ __launch_bounds__(1024) void prep(const float* __restrict__ in_w,
    const float* __restrict__ dwpw, const float* __restrict__ dwg,
    const float* __restrict__ d1pw, const float* __restrict__ d1g,
    const float* __restrict__ outw, const float* __restrict__ outg,
    float* __restrict__ wt) {
  int idx = blockIdx.x * 1024 + threadIdx.x;     // 8 slots * 4096
  int slot = idx >> 12, within = idx & 4095;
  int cc = within >> 6, o = within & 63;
  const float* src; const float* g;
  switch (slot) {
    case 0: src = in_w;            g = nullptr;      break;
    case 1: src = dwpw + 0 * 4096; g = dwg + 0 * 64; break;
    case 2: src = dwpw + 1 * 4096; g = dwg + 1 * 64; break;
    case 3: src = d1pw + 0 * 4096; g = d1g + 0 * 64; break;
    case 4: src = dwpw + 2 * 4096; g = dwg + 2 * 64; break;
    case 5: src = dwpw + 3 * 4096; g = dwg + 3 * 64; break;
    case 6: src = d1pw + 1 * 4096; g = d1g + 1 * 64; break;
    default: src = outw;           g = outg;         break;
  }
  float v = src[o * 64 + cc];
  if (g) v *= g[o];
  wt[slot * 4096 + within] = v;
}

// ---------- pointwise 64x64 conv (+bn+act), max-occupancy version ----------
// 3100 blocks x 256 thr. Block = 64 positions x 64 outputs. Wave w owns
// outputs [w*16, w*16+16); lane owns ONE position. Loads batched 8 deep.
// acc[16] + xv[8] keeps VGPR low -> 8 waves/SIMD; 12 blocks/CU.
template<int ACT, bool REV, bool SPAT, bool DW13>
__global__ __launch_bounds__(256) void pwk(const float* __restrict__ in,
    const float* __restrict__ wt, const float* __restrict__ bb,
    const float* __restrict__ ac, const float* __restrict__ w3,
    float* __restrict__ out, float* __restrict__ comb) {
  const int tid = threadIdx.x;
  const int lane = tid & 63;
  const int owu = (__builtin_amdgcn_readfirstlane(tid) >> 6) << 4;  // wave*16 (SGPR)
  const int p = blockIdx.x * 64 + lane;
  const int b = p / HT, ht = p - b * HT;
  const int row = ht / T_, t0 = ht - row * T_;
  float acc[16];
  #pragma unroll
  for (int oo = 0; oo < 16; ++oo) acc[oo] = bb ? bb[owu + oo] : 0.f;
  const float* xbase = in + b * CHT + (REV ? (row * T_ + (T_ - 1 - t0)) : ht);
  const float* rp0 = in + b * CHT + row * T_;
  for (int cg = 0; cg < 8; ++cg) {
    float xv[8];
    #pragma unroll
    for (int u = 0; u < 8; ++u) {
      const int c = cg * 8 + u;
      xv[u] = DW13 ? rp0[c * HT + t0] : xbase[c * HT];
    }
    if constexpr (DW13) {
      #pragma unroll
      for (int u = 0; u < 8; ++u) {
        const int c = cg * 8 + u;
        float x0 = xv[u];
        float xm = __shfl_up(x0, 1);
        float xp = __shfl_down(x0, 1);
        if (t0 == 0) xm = 0.f;
        else if (lane == 0) xm = rp0[c * HT + t0 - 1];
        if (t0 == T_ - 1) xp = 0.f;
        else if (lane == 63) xp = rp0[c * HT + t0 + 1];
        float s0 = xm * xm, s1 = x0 * x0, s2 = xp * xp;
        float acv = ac[b * 64 + c];
        xv[u] = (w3[c * 3 + 0] * s0 + w3[c * 3 + 1] * s1 + w3[c * 3 + 2] * s2) * acv;
      }
    }
    #pragma unroll
    for (int u = 0; u < 8; ++u) {
      const int c = cg * 8 + u;
      const float* wc = wt + c * 64 + owu;       // uniform address -> s_load
      float4 w0 = *(const float4*)(wc + 0);
      float4 w1 = *(const float4*)(wc + 4);
      float4 w2 = *(const float4*)(wc + 8);
      float4 w3q = *(const float4*)(wc + 12);
      float x = xv[u];
      acc[0]  += w0.x * x;  acc[1]  += w0.y * x;
      acc[2]  += w0.z * x;  acc[3]  += w0.w * x;
      acc[4]  += w1.x * x;  acc[5]  += w1.y * x;
      acc[6]  += w1.z * x;  acc[7]  += w1.w * x;
      acc[8]  += w2.x * x;  acc[9]  += w2.y * x;
      acc[10] += w2.z * x;  acc[11] += w2.w * x;
      acc[12] += w3q.x * x; acc[13] += w3q.y * x;
      acc[14] += w3q.z * x; acc[15] += w3q.w * x;
    }
  }
  float* obase = out + b * CHT + ht;
  float psum = 0.f, pmax = -3.4e38f;
  #pragma unroll
  for (int oo = 0; oo < 16; ++oo) {
    float r = act_<ACT>(acc[oo]);
    obase[(owu + oo) * HT] = r;
    if constexpr (SPAT) { psum += r; pmax = fmaxf(pmax, r); }
  }
  if constexpr (SPAT) {
    __shared__ float red[2][4][64];
    const int wv = tid >> 6;
    red[0][wv][lane] = psum;
    red[1][wv][lane] = pmax;
    __syncthreads();
    if (tid < 64) {
      float s = red[0][0][tid] + red[0][1][tid] + red[0][2][tid] + red[0][3][tid];
      float m = fmaxf(fmaxf(red[1][0][tid], red[1][1][tid]),
                      fmaxf(red[1][2][tid], red[1][3][tid]));
      int pp = blockIdx.x * 64 + tid;
      int b2 = pp / HT, ht2 = pp - b2 * HT;
      comb[b2 * 2 * HT + ht2] = s * (1.f / 64.f);
      comb[b2 * 2 * HT + HT + ht2] = m;
    }
  }
}

// ---------- dual 5x5 depthwise conv (both branches), pad 2 ----------
__global__ __launch_bounds__(256) void dw5dual(const float* __restrict__ in,
    const float* __restrict__ w0_, const float* __restrict__ w1_,
    float* __restrict__ out0, float* __restrict__ out1) {
  const int bc = blockIdx.y;
  const int c = bc & 63;
  int task = blockIdx.x * 256 + threadIdx.x;
  if (task >= 6200) return;                // 62 rows * 100 quads
  int h = task / 100;
  int t0 = (task - h * 100) << 2;
  const float* base = in + bc * HT;
  float win[5][12];
  const bool fast = (t0 >= 4) && (t0 <= 392);
  #pragma unroll
  for (int u = 0; u < 5; ++u) {
    int hh = h + u - 2;
    if (hh >= 0 && hh < H_) {
      const float* row = base + hh * T_;
      if (fast) {
        #pragma unroll
        for (int j = 0; j < 3; ++j)
          *(float4*)&win[u][4 * j] = *(const float4*)&row[t0 - 4 + 4 * j];
      } else {
        #pragma unroll
        for (int k = 0; k < 12; ++k) {
          int tt = t0 - 4 + k;
          win[u][k] = (tt >= 0 && tt < T_) ? row[tt] : 0.f;
        }
      }
    } else {
      #pragma unroll
      for (int k = 0; k < 12; ++k) win[u][k] = 0.f;
    }
  }
  float o0[4] = {0.f, 0.f, 0.f, 0.f};
  float o1[4] = {0.f, 0.f, 0.f, 0.f};
  #pragma unroll
  for (int u = 0; u < 5; ++u)
    #pragma unroll
    for (int v = 0; v < 5; ++v) {
      float wa = w0_[c * 25 + u * 5 + v];     // uniform -> SGPR
      float wb = w1_[c * 25 + u * 5 + v];
      #pragma unroll
      for (int j = 0; j < 4; ++j) {
        float x = win[u][j + v + 2];
        o0[j] += wa * x;
        o1[j] += wb * x;
      }
    }
  *(float4*)&out0[bc * HT + h * T_ + t0] = make_float4(o0[0], o0[1], o0[2], o0[3]);
  *(float4*)&out1[bc * HT + h * T_ + t0] = make_float4(o1[0], o1[1], o1[2], o1[3]);
}

// ---------- channel attention: raw-sum+max over half a (H,T) plane ----------
__global__ __launch_bounds__(256) void chanred(const float* __restrict__ in,
    float* __restrict__ sum_, float* __restrict__ max_) {
  int bc = blockIdx.x >> 1, hf = blockIdx.x & 1;
  const float* base = in + (size_t)bc * HT + hf * (HT / 2);
  float s = 0.f, m = -3.4e38f;
  for (int i = threadIdx.x; i < HT / 2; i += 256) {
    float v = base[i];
    s += v; m = fmaxf(m, v);
  }
  #pragma unroll
  for (int off = 32; off > 0; off >>= 1) {
    s += __shfl_down(s, off);
    m = fmaxf(m, __shfl_down(m, off));
  }
  __shared__ float ss[4], sm[4];
  int wv = threadIdx.x >> 6;
  if ((threadIdx.x & 63) == 0) { ss[wv] = s; sm[wv] = m; }
  __syncthreads();
  if (threadIdx.x == 0) {
    float S = ss[0] + ss[1] + ss[2] + ss[3];
    float M = fmaxf(fmaxf(sm[0], sm[1]), fmaxf(sm[2], sm[3]));
    sum_[hf * 512 + bc] = S;
    max_[hf * 512 + bc] = M;
  }
}

// ---------- channel attention FC: ac[b,c] = sigmoid(fc(avg)+fc(max)) ----------
__global__ __launch_bounds__(512) void cafc(const float* __restrict__ cs,
    const float* __restrict__ cm, const float* __restrict__ w1,
    const float* __restrict__ w2, float* __restrict__ ac) {
  __shared__ float sa[512], sx[512], hsum[8][4];
  int tid = threadIdx.x;
  sa[tid] = (cs[tid] + cs[512 + tid]) * (1.f / HT);
  sx[tid] = fmaxf(cm[tid], cm[512 + tid]);
  __syncthreads();
  if (tid < 32) {
    int b = tid >> 2, m = tid & 3;
    float s1 = 0.f, s2 = 0.f;
    #pragma unroll
    for (int cc = 0; cc < 64; ++cc) {
      float wv = w1[m * 64 + cc];
      s1 += sa[b * 64 + cc] * wv;
      s2 += sx[b * 64 + cc] * wv;
    }
    hsum[b][m] = fmaxf(s1, 0.f) + fmaxf(s2, 0.f);
  }
  __syncthreads();
  int b = tid >> 6, cc = tid & 63;
  float f = 0.f;
  #pragma unroll
  for (int m = 0; m < 4; ++m) f += hsum[b][m] * w2[cc * 4 + m];
  ac[tid] = sigmoidf_(f);
}

// ---------- 7x7 conv over 2 channels + sigmoid (LDS row-pair tile) ----------
__global__ __launch_bounds__(256) void conv7(const float* __restrict__ comb,
    const float* __restrict__ w, float* __restrict__ as_) {
  __shared__ float sm[2][8][408];
  __shared__ float sw[98];
  const int b = blockIdx.x / 31, hp = blockIdx.x % 31;
  const int h0 = hp * 2;
  const float* cb0 = comb + b * 2 * HT;
  const int tid = threadIdx.x;
  if (tid < 98) sw[tid] = w[tid];
  for (int e = tid; e < 2 * 8 * 408; e += 256) {
    int ci = e / 3264, rem = e - ci * 3264;
    int r = rem / 408, tt = rem - r * 408;
    int hh = h0 - 3 + r, t = tt - 4;
    float v = 0.f;
    if (hh >= 0 && hh < H_ && t >= 0 && t < T_) v = cb0[ci * HT + hh * T_ + t];
    sm[ci][r][tt] = v;
  }
  __syncthreads();
  for (int o = tid; o < 800; o += 256) {
    int oh = o / 400, ot = o - oh * 400;
    float acc = 0.f;
    #pragma unroll
    for (int ci = 0; ci < 2; ++ci)
      #pragma unroll
      for (int u = 0; u < 7; ++u)
        #pragma unroll
        for (int v = 0; v < 7; ++v)
          acc += sw[ci * 49 + u * 7 + v] * sm[ci][oh + u][ot + v + 1];
    as_[b * HT + (h0 + oh) * T_ + ot] = sigmoidf_(acc);
  }
}

// ---------- ssmctA: build P[i]=A^(2^i), q[i]=s_(2^i) tables (per half) ----------
__global__ __launch_bounds__(1024) void ssmctA(const float* __restrict__ A_,
    const float* __restrict__ Bv_, float* __restrict__ Pg, float* __restrict__ qg) {
  const int hf = blockIdx.x;
  const float* A = A_ + hf * 1024;
  const float* Bv = Bv_ + hf * 32;
  __shared__ float Pbuf[2][32 * 33];
  __shared__ float qbuf[2][32];
  const int tid = threadIdx.x;
  float* Pc = Pbuf[0]; float* Pn = Pbuf[1];
  float* qc = qbuf[0]; float* qn = qbuf[1];
  Pc[(tid >> 5) * 33 + (tid & 31)] = A[tid];
  if (tid < 32) qc[tid] = Bv[tid];
  __syncthreads();
  for (int i = 0; i < 9; ++i) {
    Pg[(hf * 9 + i) * 1024 + tid] = Pc[(tid >> 5) * 33 + (tid & 31)];
    if (tid < 32) qg[(hf * 9 + i) * 32 + tid] = qc[tid];
    if (i == 8) break;
    const int r = tid >> 5, cc = tid & 31;
    float s0 = 0.f, s1 = 0.f, s2 = 0.f, s3 = 0.f;
    #pragma unroll
    for (int k = 0; k < 32; k += 4) {
      s0 += Pc[r * 33 + k + 0] * Pc[(k + 0) * 33 + cc];
      s1 += Pc[r * 33 + k + 1] * Pc[(k + 1) * 33 + cc];
      s2 += Pc[r * 33 + k + 2] * Pc[(k + 2) * 33 + cc];
      s3 += Pc[r * 33 + k + 3] * Pc[(k + 3) * 33 + cc];
    }
    float qv = 0.f;
    if (tid < 32) {
      float a0 = 0.f, a1 = 0.f;
      #pragma unroll
      for (int k = 0; k < 32; k += 2) {
        a0 += Pc[tid * 33 + k] * qc[k];
        a1 += Pc[tid * 33 + k + 1] * qc[k + 1];
      }
      qv = qc[tid] + a0 + a1;
    }
    Pn[r * 33 + cc] = s0 + s1 + s2 + s3;
    if (tid < 32) qn[tid] = qv;
    __syncthreads();
    float* tp = Pc; Pc = Pn; Pn = tp;
    float* tq = qc; qc = qn; qn = tq;
  }
}

// ---------- ssmctB: per-t bit-walk (32 lanes hold the state), ct = s@Cm ----------
__global__ __launch_bounds__(1024) void ssmctB(const float* __restrict__ Pg,
    const float* __restrict__ qg, const float* __restrict__ Cm_,
    float* __restrict__ ct) {
  const int hf = blockIdx.y;
  __shared__ float P[9][32][33];
  __shared__ float q[9][32];
  __shared__ float Cs[32 * 64];
  __shared__ float st[32][33];
  const int tid = threadIdx.x;
  #pragma unroll
  for (int i = 0; i < 9; ++i) {
    int rem = tid;
    P[i][rem >> 5][rem & 31] = Pg[(hf * 9 + i) * 1024 + rem];
  }
  if (tid < 9 * 32) q[tid >> 5][tid & 31] = qg[hf * 9 * 32 + tid];
  for (int e = tid; e < 2048; e += 1024) Cs[e] = Cm_[hf * 2048 + e];
  __syncthreads();
  const int grp = tid >> 5, j = tid & 31;
  const int tIdx = blockIdx.x * 32 + grp;
  const int n = tIdx + 1;
  float s = 0.f;
  #pragma unroll
  for (int i = 0; i < 9; ++i) {
    st[grp][j] = s;                        // in-wave exchange (no barrier)
    float a0 = q[i][j], a1 = 0.f;
    #pragma unroll
    for (int k = 0; k < 32; k += 2) {
      a0 += P[i][j][k] * st[grp][k];
      a1 += P[i][j][k + 1] * st[grp][k + 1];
    }
    s = ((n >> i) & 1) ? (a0 + a1) : s;
  }
  st[grp][j] = s;
  __syncthreads();
  #pragma unroll
  for (int e0 = 0; e0 < 2048; e0 += 1024) {
    int e = e0 + tid;
    int ts = e >> 6, c = e & 63;
    float a0 = 0.f, a1 = 0.f;
    #pragma unroll
    for (int k = 0; k < 32; k += 2) {
      a0 += st[ts][k] * Cs[k * 64 + c];
      a1 += st[ts][k + 1] * Cs[(k + 1) * 64 + c];
    }
    int tg = blockIdx.x * 32 + ts;
    if (tg < T_) ct[(hf * T_ + tg) * 64 + c] = a0 + a1;
  }
}

// ---------- fused SSM pointwise + residual + LayerNorm(channel) + spatial gate ----
__global__ __launch_bounds__(256) void k8(const float* __restrict__ cb,
    const float* __restrict__ b2, const float* __restrict__ as_,
    const float* __restrict__ ct, const float* __restrict__ D,
    const float* __restrict__ lng, const float* __restrict__ lnb,
    float* __restrict__ out, int rev) {
  __shared__ float ct_s[64 * 65];
  __shared__ float red[4 * 2 * 66];
  const int tid = threadIdx.x;
  const int pl = tid & 63, wg = tid >> 6;
  const int p0 = blockIdx.x * 64;
  #pragma unroll
  for (int k = 0; k < 16; ++k) {
    int idx = k * 256 + tid;
    int r = idx >> 6, c2 = idx & 63;
    int t = (p0 + r) % T_;
    ct_s[r * 65 + c2] = ct[t * C_ + c2];
  }
  const int p = p0 + pl;
  const int b = p / HT, ht = p - b * HT;
  const int h = ht / T_, t = ht - h * T_;
  __syncthreads();
  const float* cbp = cb + b * CHT + ht;
  const float* b2p = b2 + b * CHT + ht;
  float o[16];
  float sum = 0.f;
  #pragma unroll
  for (int i = 0; i < 16; ++i) {
    int c = wg * 16 + i;
    float xv = cbp[c * HT];
    int c2 = (62 * c + h) & 63;          // reshape(b*h, c, t) scrambling
    float u = ct_s[pl * 65 + c2] + xv * D[c2];
    float v = xv + gelu_(u);
    o[i] = v; sum += v;
  }
  red[wg * 132 + pl] = sum;
  __syncthreads();
  float S = red[0 * 132 + pl] + red[1 * 132 + pl] + red[2 * 132 + pl] + red[3 * 132 + pl];
  float mu = S * (1.f / 64.f);
  float vp = 0.f;
  #pragma unroll
  for (int i = 0; i < 16; ++i) { float d = o[i] - mu; vp += d * d; }
  red[wg * 132 + 66 + pl] = vp;
  __syncthreads();
  float Q = red[0 * 132 + 66 + pl] + red[1 * 132 + 66 + pl] +
            red[2 * 132 + 66 + pl] + red[3 * 132 + 66 + pl];
  float rstd = rsqrtf(Q * (1.f / 64.f) + 1e-5f);
  float av = as_[p];
  int htw = rev ? (h * T_ + (T_ - 1 - t)) : ht;
  float* op = out + b * CHT + htw;
  #pragma unroll
  for (int i = 0; i < 16; ++i) {
    int c = wg * 16 + i;
    float y = (o[i] - mu) * rstd * lng[c] + lnb[c];
    float bv = b2p[c * HT];
    op[c * HT] = y * sigmoidf_(bv * bv * av);
  }
}

extern "C" void kernel_launch(void* const* d_in, const int* in_sizes, int n_in,
                              void* d_out, int out_size, void* d_ws, size_t ws_size,
                              hipStream_t stream) {
  const float* x    = (const float*)d_in[0];
  const float* in_w = (const float*)d_in[1];
  const float* dwdw = (const float*)d_in[2];
  const float* dwpw = (const float*)d_in[3];
  const float* dwg  = (const float*)d_in[4];
  const float* dwb  = (const float*)d_in[5];
  const float* caw1 = (const float*)d_in[6];
  const float* caw2 = (const float*)d_in[7];
  const float* saw  = (const float*)d_in[8];
  const float* d1dw = (const float*)d_in[9];
  const float* d1pw = (const float*)d_in[10];
  const float* d1g  = (const float*)d_in[11];
  const float* d1b  = (const float*)d_in[12];
  const float* ssmA = (const float*)d_in[13];
  const float* ssmBv= (const float*)d_in[14];
  const float* ssmC = (const float*)d_in[15];
  const float* ssmD = (const float*)d_in[16];
  const float* lng  = (const float*)d_in[17];
  const float* lnb  = (const float*)d_in[18];
  const float* outw = (const float*)d_in[19];
  const float* outg = (const float*)d_in[20];
  const float* outb = (const float*)d_in[21];

  size_t need = (size_t)(3 * (size_t)NTOT + 2 * NPOS + NPOS + 1024 + 1024 + 512
                         + 2 * T_ * C_ + 2 * 9 * 1024 + 2 * 9 * 32 + 8 * 4096) * 4;
  if (ws_size < need) return;

  float* W0 = (float*)d_ws;
  float* W1 = W0 + NTOT;
  float* W2 = W1 + NTOT;
  float* comb  = W2 + NTOT;        // B*2*HT
  float* as_   = comb + 2 * NPOS;  // B*HT
  float* casum = as_ + NPOS;       // 1024
  float* camax = casum + 1024;     // 1024
  float* ac    = camax + 1024;     // 512
  float* ct    = ac + 512;         // 2*T*C
  float* Pg    = ct + 2 * T_ * C_; // 2*9*1024
  float* qg    = Pg + 2 * 9 * 1024;// 2*9*32
  float* wt    = qg + 2 * 9 * 32;  // 8*4096 transposed weights

  prep<<<32, 1024, 0, stream>>>(in_w, dwpw, dwg, d1pw, d1g, outw, outg, wt);
  ssmctA<<<2, 1024, 0, stream>>>(ssmA, ssmBv, Pg, qg);
  ssmctB<<<dim3(13, 2), 1024, 0, stream>>>(Pg, qg, ssmC, ct);
  pwk<0, false, false, false><<<3100, 256, 0, stream>>>(x, wt, nullptr,
                                                        nullptr, nullptr, W0, nullptr);

  auto run_half = [&](int hf, float* X, float* Fa, float* Fb) {
    const float* dw0 = dwdw + (hf * 2 + 0) * C_ * 25;
    const float* dw1 = dwdw + (hf * 2 + 1) * C_ * 25;
    const float* b0  = dwb + (hf * 2 + 0) * C_;
    const float* b1w = dwb + (hf * 2 + 1) * C_;
    dw5dual<<<dim3(25, 512), 256, 0, stream>>>(X, dw0, dw1, Fa, Fb);
    pwk<1, false, false, false><<<3100, 256, 0, stream>>>(Fa, wt + (1 + hf * 3) * 4096,
                                                          b0, nullptr, nullptr, X, nullptr);  // b1 -> X
    pwk<1, false, true, false><<<3100, 256, 0, stream>>>(Fb, wt + (2 + hf * 3) * 4096,
                                                         b1w, nullptr, nullptr, Fa, comb);    // b2 -> Fa
    chanred<<<1024, 256, 0, stream>>>(X, casum, camax);
    cafc<<<1, 512, 0, stream>>>(casum, camax, caw1 + hf * 4 * 64, caw2 + hf * 64 * 4, ac);
    conv7<<<248, 256, 0, stream>>>(comb, saw + hf * 98, as_);
    // cb = sigmoid(bn(pw(dw1x3(b1^2*ac)))) -> Fb
    pwk<2, false, false, true><<<3100, 256, 0, stream>>>(X, wt + (3 + hf * 3) * 4096,
                                                         d1b + hf * C_, ac,
                                                         d1dw + hf * C_ * 3, Fb, nullptr);
    k8<<<3100, 256, 0, stream>>>(Fb, Fa, as_, ct + hf * T_ * C_,
                                 ssmD + hf * C_, lng + hf * C_, lnb + hf * C_,
                                 X, hf == 0 ? 1 : 0);
  };

  run_half(0, W0, W1, W2);     // k8 writes reversed -> W0 (= input of half 1)
  run_half(1, W0, W1, W2);     // k8 writes (reversed domain) -> W0
  // final pw reads W0 with reversed-t (undo), + bn + relu -> d_out
  pwk<1, true, false, false><<<3100, 256, 0, stream>>>(W0, wt + 7 * 4096, outb,
                                                       nullptr, nullptr,
                                                       (float*)d_out, nullptr);
}

// Round 9
// 421.366 us; speedup vs baseline: 1.4435x; 1.4435x over previous
//
#include <hip/hip_runtime.h>
#include <math.h>

#define DI __device__ __forceinline__

constexpr int B_ = 8, C_ = 64, H_ = 62, T_ = 400, S_ = 32;
constexpr int HT   = H_ * T_;      // 24800
constexpr int CHT  = C_ * HT;      // 1587200
constexpr int NPOS = B_ * HT;      // 198400
constexpr int NTOT = B_ * CHT;     // 12697600

typedef __attribute__((ext_vector_type(8))) short short8;
typedef __attribute__((ext_vector_type(4))) float float4v;

DI float sigmoidf_(float x) { return 1.f / (1.f + expf(-x)); }
DI float gelu_(float x) { return 0.5f * x * (1.f + erff(x * 0.70710678118654752f)); }

template<int ACT> DI float act_(float v) {
  if (ACT == 1) return fmaxf(v, 0.f);
  if (ACT == 2) return sigmoidf_(v);
  return v;
}

DI unsigned short f2b(float f) {            // fp32 -> bf16 RNE
  unsigned int u = __float_as_uint(f);
  u += 0x7FFFu + ((u >> 16) & 1u);
  return (unsigned short)(u >> 16);
}
DI unsigned int pk2(float a, float b) {
  return (unsigned int)f2b(a) | ((unsigned int)f2b(b) << 16);
}

// ---------- prep: weights -> bf16 A-fragment layout, bn gain folded ----------
// frag layout (mfma_f32_16x16x32_bf16 A): lane holds A[m=lane&15][k=(lane>>4)*8+i]
// flat: wf[(((slot*4+w)*2+kc)*64+lane)*8+i],  o = w*16+m, c = kc*32+(lane>>4)*8+i
__global__ __launch_bounds__(256) void prep(const float* __restrict__ in_w,
    const float* __restrict__ dwpw, const float* __restrict__ dwg,
    const float* __restrict__ d1pw, const float* __restrict__ d1g,
    const float* __restrict__ outw, const float* __restrict__ outg,
    unsigned short* __restrict__ wf) {
  int idx = blockIdx.x * 256 + threadIdx.x;     // 4096 fragments
  int lane = idx & 63, kc = (idx >> 6) & 1, w = (idx >> 7) & 3, slot = idx >> 9;
  const float* src; const float* g;
  switch (slot) {
    case 0: src = in_w;            g = nullptr;      break;
    case 1: src = dwpw + 0 * 4096; g = dwg + 0 * 64; break;
    case 2: src = dwpw + 1 * 4096; g = dwg + 1 * 64; break;
    case 3: src = d1pw + 0 * 4096; g = d1g + 0 * 64; break;
    case 4: src = dwpw + 2 * 4096; g = dwg + 2 * 64; break;
    case 5: src = dwpw + 3 * 4096; g = dwg + 3 * 64; break;
    case 6: src = d1pw + 1 * 4096; g = d1g + 1 * 64; break;
    default: src = outw;           g = outg;         break;
  }
  int o = w * 16 + (lane & 15);
  float gv = g ? g[o] : 1.f;
  unsigned int pack[4];
  #pragma unroll
  for (int h = 0; h < 4; ++h) {
    int c = kc * 32 + (lane >> 4) * 8 + h * 2;
    pack[h] = pk2(src[o * 64 + c] * gv, src[o * 64 + c + 1] * gv);
  }
  *(uint4*)&wf[idx * 8] = make_uint4(pack[0], pack[1], pack[2], pack[3]);
}

// ---------- pointwise 64x64 conv via MFMA (+bias+act, REV/SPAT/DW13 fused) ----
// 3100 blocks x 256 thr. Block = 64 positions x 64 outputs, K=64.
// X staged to LDS as bf16 [p][c] (stride 72, XOR-swizzled cols).
// Wave w owns o-rows [w*16,w*16+16); 4 N-tiles x 2 K-chunks = 8 MFMA.
template<int ACT, bool REV, bool SPAT, bool DW13>
__global__ __launch_bounds__(256) void pwk(const float* __restrict__ in,
    const unsigned short* __restrict__ wf, const float* __restrict__ bb,
    const float* __restrict__ ac, const float* __restrict__ w3,
    float* __restrict__ out, float* __restrict__ comb) {
  __shared__ unsigned short Xb[64 * 72];
  const int tid = threadIdx.x;
  const int lane = tid & 63;
  const int wv = tid >> 6;
  const int p0 = blockIdx.x * 64;
  // ---- stage X tile: thread = 4 positions (ps..ps+3) x 4 channels (cs..cs+3)
  {
    const int ps = (tid & 15) * 4;
    const int cs = (tid >> 4) * 4;
    const int p4 = p0 + ps;
    const int b = p4 / HT, ht = p4 - b * HT;
    const int row = ht / T_, t0 = ht - row * T_;
    const float* rp0 = in + b * CHT + row * T_;
    float xv[4][4];
    #pragma unroll
    for (int cj = 0; cj < 4; ++cj) {
      const int c = cs + cj;
      const float* rp = rp0 + c * HT;
      if constexpr (DW13) {
        float4 xc = *(const float4*)&rp[t0];
        float xm = (t0 > 0)       ? rp[t0 - 1] : 0.f;
        float xp = (t0 < T_ - 4)  ? rp[t0 + 4] : 0.f;
        float s0 = xm * xm, s1 = xc.x * xc.x, s2 = xc.y * xc.y;
        float s3 = xc.z * xc.z, s4 = xc.w * xc.w, s5 = xp * xp;
        float acv = ac[b * 64 + c];
        float c0 = w3[c * 3 + 0] * acv, c1 = w3[c * 3 + 1] * acv,
              c2 = w3[c * 3 + 2] * acv;
        xv[cj][0] = c0 * s0 + c1 * s1 + c2 * s2;
        xv[cj][1] = c0 * s1 + c1 * s2 + c2 * s3;
        xv[cj][2] = c0 * s2 + c1 * s3 + c2 * s4;
        xv[cj][3] = c0 * s3 + c1 * s4 + c2 * s5;
      } else if constexpr (REV) {
        float4 u = *(const float4*)&rp[T_ - 4 - t0];
        xv[cj][0] = u.w; xv[cj][1] = u.z; xv[cj][2] = u.y; xv[cj][3] = u.x;
      } else {
        float4 u = *(const float4*)&rp[t0];
        xv[cj][0] = u.x; xv[cj][1] = u.y; xv[cj][2] = u.z; xv[cj][3] = u.w;
      }
    }
    #pragma unroll
    for (int pi = 0; pi < 4; ++pi) {
      int r = ps + pi;
      int col = cs ^ (((r >> 2) & 7) << 3);       // swizzle (8-ushort blocks)
      *(uint2*)&Xb[r * 72 + col] =
          make_uint2(pk2(xv[0][pi], xv[1][pi]), pk2(xv[2][pi], xv[3][pi]));
    }
  }
  // ---- A fragments (weights), coalesced 16B per lane
  short8 af0 = *(const short8*)(wf + ((wv * 2 + 0) * 64 + lane) * 8);
  short8 af1 = *(const short8*)(wf + ((wv * 2 + 1) * 64 + lane) * 8);
  const int m4 = (lane >> 4) * 4;
  float binit[4];
  #pragma unroll
  for (int j = 0; j < 4; ++j) binit[j] = bb ? bb[wv * 16 + m4 + j] : 0.f;
  __syncthreads();
  // ---- MFMA: 4 N-tiles x 2 K-chunks
  float4v acc[4];
  #pragma unroll
  for (int nt = 0; nt < 4; ++nt) { acc[nt][0] = acc[nt][1] = acc[nt][2] = acc[nt][3] = 0.f; }
  #pragma unroll
  for (int nt = 0; nt < 4; ++nt) {
    int r = nt * 16 + (lane & 15);
    int sw = ((r >> 2) & 7) << 3;
    int cb0 = ((lane >> 4) * 8) ^ sw;
    int cb1 = (32 + (lane >> 4) * 8) ^ sw;
    short8 b0 = *(const short8*)&Xb[r * 72 + cb0];
    short8 b1 = *(const short8*)&Xb[r * 72 + cb1];
    acc[nt] = __builtin_amdgcn_mfma_f32_16x16x32_bf16(af0, b0, acc[nt], 0, 0, 0);
    acc[nt] = __builtin_amdgcn_mfma_f32_16x16x32_bf16(af1, b1, acc[nt], 0, 0, 0);
  }
  // ---- epilogue: bias + act + store (+SPAT reduce)
  float psum[4], pmaxv[4];
  #pragma unroll
  for (int nt = 0; nt < 4; ++nt) {
    int n = nt * 16 + (lane & 15);
    int p = p0 + n;
    int b = p / HT, ht = p - b * HT;
    float* op = out + b * CHT + ht + (wv * 16 + m4) * HT;
    float s = 0.f, m = -3.4e38f;
    #pragma unroll
    for (int j = 0; j < 4; ++j) {
      float r = act_<ACT>(acc[nt][j] + binit[j]);
      op[j * HT] = r;
      if constexpr (SPAT) { s += r; m = fmaxf(m, r); }
    }
    if constexpr (SPAT) {
      s += __shfl_xor(s, 16); s += __shfl_xor(s, 32);
      m = fmaxf(m, __shfl_xor(m, 16)); m = fmaxf(m, __shfl_xor(m, 32));
      psum[nt] = s; pmaxv[nt] = m;
    }
  }
  if constexpr (SPAT) {
    __shared__ float redS[4][64], redM[4][64];
    if (lane < 16) {
      #pragma unroll
      for (int nt = 0; nt < 4; ++nt) {
        redS[wv][nt * 16 + lane] = psum[nt];
        redM[wv][nt * 16 + lane] = pmaxv[nt];
      }
    }
    __syncthreads();
    if (tid < 64) {
      float s = redS[0][tid] + redS[1][tid] + redS[2][tid] + redS[3][tid];
      float m = fmaxf(fmaxf(redM[0][tid], redM[1][tid]),
                      fmaxf(redM[2][tid], redM[3][tid]));
      int pp = p0 + tid;
      int b2 = pp / HT, ht2 = pp - b2 * HT;
      comb[b2 * 2 * HT + ht2] = s * (1.f / 64.f);
      comb[b2 * 2 * HT + HT + ht2] = m;
    }
  }
}

// ---------- dual 5x5 depthwise conv (both branches), pad 2 ----------
__global__ __launch_bounds__(256) void dw5dual(const float* __restrict__ in,
    const float* __restrict__ w0_, const float* __restrict__ w1_,
    float* __restrict__ out0, float* __restrict__ out1) {
  const int bc = blockIdx.y;
  const int c = bc & 63;
  int task = blockIdx.x * 256 + threadIdx.x;
  if (task >= 6200) return;                // 62 rows * 100 quads
  int h = task / 100;
  int t0 = (task - h * 100) << 2;
  const float* base = in + bc * HT;
  float win[5][12];
  const bool fast = (t0 >= 4) && (t0 <= 392);
  #pragma unroll
  for (int u = 0; u < 5; ++u) {
    int hh = h + u - 2;
    if (hh >= 0 && hh < H_) {
      const float* row = base + hh * T_;
      if (fast) {
        #pragma unroll
        for (int j = 0; j < 3; ++j)
          *(float4*)&win[u][4 * j] = *(const float4*)&row[t0 - 4 + 4 * j];
      } else {
        #pragma unroll
        for (int k = 0; k < 12; ++k) {
          int tt = t0 - 4 + k;
          win[u][k] = (tt >= 0 && tt < T_) ? row[tt] : 0.f;
        }
      }
    } else {
      #pragma unroll
      for (int k = 0; k < 12; ++k) win[u][k] = 0.f;
    }
  }
  float o0[4] = {0.f, 0.f, 0.f, 0.f};
  float o1[4] = {0.f, 0.f, 0.f, 0.f};
  #pragma unroll
  for (int u = 0; u < 5; ++u)
    #pragma unroll
    for (int v = 0; v < 5; ++v) {
      float wa = w0_[c * 25 + u * 5 + v];     // uniform -> SGPR
      float wb = w1_[c * 25 + u * 5 + v];
      #pragma unroll
      for (int j = 0; j < 4; ++j) {
        float x = win[u][j + v + 2];
        o0[j] += wa * x;
        o1[j] += wb * x;
      }
    }
  *(float4*)&out0[bc * HT + h * T_ + t0] = make_float4(o0[0], o0[1], o0[2], o0[3]);
  *(float4*)&out1[bc * HT + h * T_ + t0] = make_float4(o1[0], o1[1], o1[2], o1[3]);
}

// ---------- channel attention: raw-sum+max over half a (H,T) plane ----------
__global__ __launch_bounds__(256) void chanred(const float* __restrict__ in,
    float* __restrict__ sum_, float* __restrict__ max_) {
  int bc = blockIdx.x >> 1, hf = blockIdx.x & 1;
  const float* base = in + (size_t)bc * HT + hf * (HT / 2);
  float s = 0.f, m = -3.4e38f;
  for (int i = threadIdx.x; i < HT / 2; i += 256) {
    float v = base[i];
    s += v; m = fmaxf(m, v);
  }
  #pragma unroll
  for (int off = 32; off > 0; off >>= 1) {
    s += __shfl_down(s, off);
    m = fmaxf(m, __shfl_down(m, off));
  }
  __shared__ float ss[4], sm[4];
  int wv = threadIdx.x >> 6;
  if ((threadIdx.x & 63) == 0) { ss[wv] = s; sm[wv] = m; }
  __syncthreads();
  if (threadIdx.x == 0) {
    float S = ss[0] + ss[1] + ss[2] + ss[3];
    float M = fmaxf(fmaxf(sm[0], sm[1]), fmaxf(sm[2], sm[3]));
    sum_[hf * 512 + bc] = S;
    max_[hf * 512 + bc] = M;
  }
}

// ---------- channel attention FC: ac[b,c] = sigmoid(fc(avg)+fc(max)) ----------
__global__ __launch_bounds__(512) void cafc(const float* __restrict__ cs,
    const float* __restrict__ cm, const float* __restrict__ w1,
    const float* __restrict__ w2, float* __restrict__ ac) {
  __shared__ float sa[512], sx[512], hsum[8][4];
  int tid = threadIdx.x;
  sa[tid] = (cs[tid] + cs[512 + tid]) * (1.f / HT);
  sx[tid] = fmaxf(cm[tid], cm[512 + tid]);
  __syncthreads();
  if (tid < 32) {
    int b = tid >> 2, m = tid & 3;
    float s1 = 0.f, s2 = 0.f;
    #pragma unroll
    for (int cc = 0; cc < 64; ++cc) {
      float wv = w1[m * 64 + cc];
      s1 += sa[b * 64 + cc] * wv;
      s2 += sx[b * 64 + cc] * wv;
    }
    hsum[b][m] = fmaxf(s1, 0.f) + fmaxf(s2, 0.f);
  }
  __syncthreads();
  int b = tid >> 6, cc = tid & 63;
  float f = 0.f;
  #pragma unroll
  for (int m = 0; m < 4; ++m) f += hsum[b][m] * w2[cc * 4 + m];
  ac[tid] = sigmoidf_(f);
}

// ---------- 7x7 conv over 2 channels + sigmoid (LDS row-pair tile) ----------
__global__ __launch_bounds__(256) void conv7(const float* __restrict__ comb,
    const float* __restrict__ w, float* __restrict__ as_) {
  __shared__ float sm[2][8][408];
  __shared__ float sw[98];
  const int b = blockIdx.x / 31, hp = blockIdx.x % 31;
  const int h0 = hp * 2;
  const float* cb0 = comb + b * 2 * HT;
  const int tid = threadIdx.x;
  if (tid < 98) sw[tid] = w[tid];
  for (int e = tid; e < 2 * 8 * 408; e += 256) {
    int ci = e / 3264, rem = e - ci * 3264;
    int r = rem / 408, tt = rem - r * 408;
    int hh = h0 - 3 + r, t = tt - 4;
    float v = 0.f;
    if (hh >= 0 && hh < H_ && t >= 0 && t < T_) v = cb0[ci * HT + hh * T_ + t];
    sm[ci][r][tt] = v;
  }
  __syncthreads();
  for (int o = tid; o < 800; o += 256) {
    int oh = o / 400, ot = o - oh * 400;
    float acc = 0.f;
    #pragma unroll
    for (int ci = 0; ci < 2; ++ci)
      #pragma unroll
      for (int u = 0; u < 7; ++u)
        #pragma unroll
        for (int v = 0; v < 7; ++v)
          acc += sw[ci * 49 + u * 7 + v] * sm[ci][oh + u][ot + v + 1];
    as_[b * HT + (h0 + oh) * T_ + ot] = sigmoidf_(acc);
  }
}

// ---------- ssmctA: build P[i]=A^(2^i), q[i]=s_(2^i) tables (per half) ----------
__global__ __launch_bounds__(1024) void ssmctA(const float* __restrict__ A_,
    const float* __restrict__ Bv_, float* __restrict__ Pg, float* __restrict__ qg) {
  const int hf = blockIdx.x;
  const float* A = A_ + hf * 1024;
  const float* Bv = Bv_ + hf * 32;
  __shared__ float Pbuf[2][32 * 33];
  __shared__ float qbuf[2][32];
  const int tid = threadIdx.x;
  float* Pc = Pbuf[0]; float* Pn = Pbuf[1];
  float* qc = qbuf[0]; float* qn = qbuf[1];
  Pc[(tid >> 5) * 33 + (tid & 31)] = A[tid];
  if (tid < 32) qc[tid] = Bv[tid];
  __syncthreads();
  for (int i = 0; i < 9; ++i) {
    Pg[(hf * 9 + i) * 1024 + tid] = Pc[(tid >> 5) * 33 + (tid & 31)];
    if (tid < 32) qg[(hf * 9 + i) * 32 + tid] = qc[tid];
    if (i == 8) break;
    const int r = tid >> 5, cc = tid & 31;
    float s0 = 0.f, s1 = 0.f, s2 = 0.f, s3 = 0.f;
    #pragma unroll
    for (int k = 0; k < 32; k += 4) {
      s0 += Pc[r * 33 + k + 0] * Pc[(k + 0) * 33 + cc];
      s1 += Pc[r * 33 + k + 1] * Pc[(k + 1) * 33 + cc];
      s2 += Pc[r * 33 + k + 2] * Pc[(k + 2) * 33 + cc];
      s3 += Pc[r * 33 + k + 3] * Pc[(k + 3) * 33 + cc];
    }
    float qv = 0.f;
    if (tid < 32) {
      float a0 = 0.f, a1 = 0.f;
      #pragma unroll
      for (int k = 0; k < 32; k += 2) {
        a0 += Pc[tid * 33 + k] * qc[k];
        a1 += Pc[tid * 33 + k + 1] * qc[k + 1];
      }
      qv = qc[tid] + a0 + a1;
    }
    Pn[r * 33 + cc] = s0 + s1 + s2 + s3;
    if (tid < 32) qn[tid] = qv;
    __syncthreads();
    float* tp = Pc; Pc = Pn; Pn = tp;
    float* tq = qc; qc = qn; qn = tq;
  }
}

// ---------- ssmctB: per-t bit-walk (32 lanes hold the state), ct = s@Cm ----------
__global__ __launch_bounds__(1024) void ssmctB(const float* __restrict__ Pg,
    const float* __restrict__ qg, const float* __restrict__ Cm_,
    float* __restrict__ ct) {
  const int hf = blockIdx.y;
  __shared__ float P[9][32][33];
  __shared__ float q[9][32];
  __shared__ float Cs[32 * 64];
  __shared__ float st[32][33];
  const int tid = threadIdx.x;
  #pragma unroll
  for (int i = 0; i < 9; ++i) {
    int rem = tid;
    P[i][rem >> 5][rem & 31] = Pg[(hf * 9 + i) * 1024 + rem];
  }
  if (tid < 9 * 32) q[tid >> 5][tid & 31] = qg[hf * 9 * 32 + tid];
  for (int e = tid; e < 2048; e += 1024) Cs[e] = Cm_[hf * 2048 + e];
  __syncthreads();
  const int grp = tid >> 5, j = tid & 31;
  const int tIdx = blockIdx.x * 32 + grp;
  const int n = tIdx + 1;
  float s = 0.f;
  #pragma unroll
  for (int i = 0; i < 9; ++i) {
    st[grp][j] = s;                        // in-wave exchange (no barrier)
    float a0 = q[i][j], a1 = 0.f;
    #pragma unroll
    for (int k = 0; k < 32; k += 2) {
      a0 += P[i][j][k] * st[grp][k];
      a1 += P[i][j][k + 1] * st[grp][k + 1];
    }
    s = ((n >> i) & 1) ? (a0 + a1) : s;
  }
  st[grp][j] = s;
  __syncthreads();
  #pragma unroll
  for (int e0 = 0; e0 < 2048; e0 += 1024) {
    int e = e0 + tid;
    int ts = e >> 6, c = e & 63;
    float a0 = 0.f, a1 = 0.f;
    #pragma unroll
    for (int k = 0; k < 32; k += 2) {
      a0 += st[ts][k] * Cs[k * 64 + c];
      a1 += st[ts][k + 1] * Cs[(k + 1) * 64 + c];
    }
    int tg = blockIdx.x * 32 + ts;
    if (tg < T_) ct[(hf * T_ + tg) * 64 + c] = a0 + a1;
  }
}

// ---------- fused SSM pointwise + residual + LayerNorm(channel) + spatial gate ----
__global__ __launch_bounds__(256) void k8(const float* __restrict__ cb,
    const float* __restrict__ b2, const float* __restrict__ as_,
    const float* __restrict__ ct, const float* __restrict__ D,
    const float* __restrict__ lng, const float* __restrict__ lnb,
    float* __restrict__ out, int rev) {
  __shared__ float ct_s[64 * 65];
  __shared__ float red[4 * 2 * 66];
  const int tid = threadIdx.x;
  const int pl = tid & 63, wg = tid >> 6;
  const int p0 = blockIdx.x * 64;
  #pragma unroll
  for (int k = 0; k < 16; ++k) {
    int idx = k * 256 + tid;
    int r = idx >> 6, c2 = idx & 63;
    int t = (p0 + r) % T_;
    ct_s[r * 65 + c2] = ct[t * C_ + c2];
  }
  const int p = p0 + pl;
  const int b = p / HT, ht = p - b * HT;
  const int h = ht / T_, t = ht - h * T_;
  __syncthreads();
  const float* cbp = cb + b * CHT + ht;
  const float* b2p = b2 + b * CHT + ht;
  float o[16];
  float sum = 0.f;
  #pragma unroll
  for (int i = 0; i < 16; ++i) {
    int c = wg * 16 + i;
    float xv = cbp[c * HT];
    int c2 = (62 * c + h) & 63;          // reshape(b*h, c, t) scrambling
    float u = ct_s[pl * 65 + c2] + xv * D[c2];
    float v = xv + gelu_(u);
    o[i] = v; sum += v;
  }
  red[wg * 132 + pl] = sum;
  __syncthreads();
  float S = red[0 * 132 + pl] + red[1 * 132 + pl] + red[2 * 132 + pl] + red[3 * 132 + pl];
  float mu = S * (1.f / 64.f);
  float vp = 0.f;
  #pragma unroll
  for (int i = 0; i < 16; ++i) { float d = o[i] - mu; vp += d * d; }
  red[wg * 132 + 66 + pl] = vp;
  __syncthreads();
  float Q = red[0 * 132 + 66 + pl] + red[1 * 132 + 66 + pl] +
            red[2 * 132 + 66 + pl] + red[3 * 132 + 66 + pl];
  float rstd = rsqrtf(Q * (1.f / 64.f) + 1e-5f);
  float av = as_[p];
  int htw = rev ? (h * T_ + (T_ - 1 - t)) : ht;
  float* op = out + b * CHT + htw;
  #pragma unroll
  for (int i = 0; i < 16; ++i) {
    int c = wg * 16 + i;
    float y = (o[i] - mu) * rstd * lng[c] + lnb[c];
    float bv = b2p[c * HT];
    op[c * HT] = y * sigmoidf_(bv * bv * av);
  }
}

extern "C" void kernel_launch(void* const* d_in, const int* in_sizes, int n_in,
                              void* d_out, int out_size, void* d_ws, size_t ws_size,
                              hipStream_t stream) {
  const float* x    = (const float*)d_in[0];
  const float* in_w = (const float*)d_in[1];
  const float* dwdw = (const float*)d_in[2];
  const float* dwpw = (const float*)d_in[3];
  const float* dwg  = (const float*)d_in[4];
  const float* dwb  = (const float*)d_in[5];
  const float* caw1 = (const float*)d_in[6];
  const float* caw2 = (const float*)d_in[7];
  const float* saw  = (const float*)d_in[8];
  const float* d1dw = (const float*)d_in[9];
  const float* d1pw = (const float*)d_in[10];
  const float* d1g  = (const float*)d_in[11];
  const float* d1b  = (const float*)d_in[12];
  const float* ssmA = (const float*)d_in[13];
  const float* ssmBv= (const float*)d_in[14];
  const float* ssmC = (const float*)d_in[15];
  const float* ssmD = (const float*)d_in[16];
  const float* lng  = (const float*)d_in[17];
  const float* lnb  = (const float*)d_in[18];
  const float* outw = (const float*)d_in[19];
  const float* outg = (const float*)d_in[20];
  const float* outb = (const float*)d_in[21];

  size_t need = (size_t)(3 * (size_t)NTOT + 2 * NPOS + NPOS + 1024 + 1024 + 512
                         + 2 * T_ * C_ + 2 * 9 * 1024 + 2 * 9 * 32 + 16384) * 4;
  if (ws_size < need) return;

  float* W0 = (float*)d_ws;
  float* W1 = W0 + NTOT;
  float* W2 = W1 + NTOT;
  float* comb  = W2 + NTOT;        // B*2*HT
  float* as_   = comb + 2 * NPOS;  // B*HT
  float* casum = as_ + NPOS;       // 1024
  float* camax = casum + 1024;     // 1024
  float* ac    = camax + 1024;     // 512
  float* ct    = ac + 512;         // 2*T*C
  float* Pg    = ct + 2 * T_ * C_; // 2*9*1024
  float* qg    = Pg + 2 * 9 * 1024;// 2*9*32
  unsigned short* Wbf = (unsigned short*)(qg + 2 * 9 * 32);  // 8 slots * 4096 bf16

  prep<<<16, 256, 0, stream>>>(in_w, dwpw, dwg, d1pw, d1g, outw, outg, Wbf);
  ssmctA<<<2, 1024, 0, stream>>>(ssmA, ssmBv, Pg, qg);
  ssmctB<<<dim3(13, 2), 1024, 0, stream>>>(Pg, qg, ssmC, ct);
  pwk<0, false, false, false><<<3100, 256, 0, stream>>>(x, Wbf + 0 * 4096, nullptr,
                                                        nullptr, nullptr, W0, nullptr);

  auto run_half = [&](int hf, float* X, float* Fa, float* Fb) {
    const float* dw0 = dwdw + (hf * 2 + 0) * C_ * 25;
    const float* dw1 = dwdw + (hf * 2 + 1) * C_ * 25;
    const float* b0  = dwb + (hf * 2 + 0) * C_;
    const float* b1w = dwb + (hf * 2 + 1) * C_;
    dw5dual<<<dim3(25, 512), 256, 0, stream>>>(X, dw0, dw1, Fa, Fb);
    pwk<1, false, false, false><<<3100, 256, 0, stream>>>(Fa, Wbf + (1 + hf * 3) * 4096,
                                                          b0, nullptr, nullptr, X, nullptr);  // b1 -> X
    pwk<1, false, true, false><<<3100, 256, 0, stream>>>(Fb, Wbf + (2 + hf * 3) * 4096,
                                                         b1w, nullptr, nullptr, Fa, comb);    // b2 -> Fa
    chanred<<<1024, 256, 0, stream>>>(X, casum, camax);
    cafc<<<1, 512, 0, stream>>>(casum, camax, caw1 + hf * 4 * 64, caw2 + hf * 64 * 4, ac);
    conv7<<<248, 256, 0, stream>>>(comb, saw + hf * 98, as_);
    // cb = sigmoid(bn(pw(dw1x3(b1^2*ac)))) -> Fb
    pwk<2, false, false, true><<<3100, 256, 0, stream>>>(X, Wbf + (3 + hf * 3) * 4096,
                                                         d1b + hf * C_, ac,
                                                         d1dw + hf * C_ * 3, Fb, nullptr);
    k8<<<3100, 256, 0, stream>>>(Fb, Fa, as_, ct + hf * T_ * C_,
                                 ssmD + hf * C_, lng + hf * C_, lnb + hf * C_,
                                 X, hf == 0 ? 1 : 0);
  };

  run_half(0, W0, W1, W2);     // k8 writes reversed -> W0 (= input of half 1)
  run_half(1, W0, W1, W2);     // k8 writes (reversed domain) -> W0
  // final pw reads W0 with reversed-t (undo), + bn + relu -> d_out
  pwk<1, true, false, false><<<3100, 256, 0, stream>>>(W0, Wbf + 7 * 4096, outb,
                                                       nullptr, nullptr,
                                                       (float*)d_out, nullptr);
}